// Round 4
// baseline (1525.372 us; speedup 1.0000x reference)
//
#include <hip/hip_runtime.h>

#define D 128
#define NBMAX 1024      // bucket arrays padded size (NB = 782)
#define CHUNK 4096      // edges per bfill block

typedef __attribute__((ext_vector_type(8))) short bf16x8;
typedef __attribute__((ext_vector_type(4))) float f32x4;

__device__ __forceinline__ unsigned short f2bf(float f) {
    unsigned int u = __builtin_bit_cast(unsigned int, f);
    u = (u + 0x7fffu + ((u >> 16) & 1u)) >> 16;
    return (unsigned short)u;
}
__device__ __forceinline__ float bf2f(unsigned int u) {
    return __builtin_bit_cast(float, u << 16);
}

__global__ void zero_int_kernel(int* __restrict__ p, int n) {
    int i = blockIdx.x * 256 + threadIdx.x;
    if (i < n) p[i] = 0;
}

// x fp32 -> bf16 (natural layout), 4 elems/thread
__global__ void xprep_kernel(const float* __restrict__ x,
                             unsigned short* __restrict__ x_bf, int n4) {
    int i = blockIdx.x * 256 + threadIdx.x;
    if (i >= n4) return;
    float4 v = ((const float4*)x)[i];
    ushort4 s; s.x = f2bf(v.x); s.y = f2bf(v.y); s.z = f2bf(v.z); s.w = f2bf(v.w);
    ((ushort4*)x_bf)[i] = s;
}

// WT[col*256 + k] = bf16(W[k*128 + col])
__global__ void wprep_kernel(const float* __restrict__ W,
                             unsigned short* __restrict__ WT) {
    int t = blockIdx.x * 256 + threadIdx.x;   // 32768
    int col = t & 127, k = t >> 7;
    WT[col * 256 + k] = f2bf(W[k * D + col]);
}

// per-bucket histogram, LDS-merged
__global__ __launch_bounds__(256) void bhist_kernel(const int* __restrict__ edst,
                                                    int* __restrict__ bucket_cnt,
                                                    int E, int NB) {
    __shared__ int h[NBMAX];
    for (int i = threadIdx.x; i < NB; i += 256) h[i] = 0;
    __syncthreads();
    int stride = gridDim.x * 256;
    for (int e = blockIdx.x * 256 + threadIdx.x; e < E; e += stride)
        atomicAdd(&h[edst[e] >> 7], 1);
    __syncthreads();
    for (int i = threadIdx.x; i < NB; i += 256) {
        int c = h[i];
        if (c) atomicAdd(&bucket_cnt[i], c);
    }
}

// single-block exclusive scan of bucket_cnt -> bucket_base, bucket_cursor
__global__ __launch_bounds__(256) void bscan_kernel(const int* __restrict__ cnt,
                                                    int* __restrict__ base,
                                                    int* __restrict__ cursor, int NB) {
    __shared__ int p[256];
    int t = threadIdx.x;
    int c0 = (4*t   < NB) ? cnt[4*t]   : 0;
    int c1 = (4*t+1 < NB) ? cnt[4*t+1] : 0;
    int c2 = (4*t+2 < NB) ? cnt[4*t+2] : 0;
    int c3 = (4*t+3 < NB) ? cnt[4*t+3] : 0;
    int loc = c0 + c1 + c2 + c3;
    p[t] = loc;
    __syncthreads();
    for (int off = 1; off < 256; off <<= 1) {
        int v = p[t];
        int u = (t >= off) ? p[t - off] : 0;
        __syncthreads();
        p[t] = v + u;
        __syncthreads();
    }
    int ex = p[t] - loc;
    int b0 = ex, b1 = ex + c0, b2 = ex + c0 + c1, b3 = ex + c0 + c1 + c2;
    if (4*t   < NB) { base[4*t]   = b0; cursor[4*t]   = b0; }
    if (4*t+1 < NB) { base[4*t+1] = b1; cursor[4*t+1] = b1; }
    if (4*t+2 < NB) { base[4*t+2] = b2; cursor[4*t+2] = b2; }
    if (4*t+3 < NB) { base[4*t+3] = b3; cursor[4*t+3] = b3; }
}

// LDS counting sort of a 4096-edge chunk into contiguous per-bucket runs.
// entry.x = src | (node_local << 20), entry.y = fp32 val bits.
__global__ __launch_bounds__(256) void bfill_kernel(const int* __restrict__ esrc,
                                                    const int* __restrict__ edst,
                                                    const float* __restrict__ eval,
                                                    int* __restrict__ bucket_cursor,
                                                    int2* __restrict__ edge_pack,
                                                    int E, int NB) {
    __shared__ int lh[NBMAX];      // per-bucket counts
    __shared__ int lstart[NBMAX];  // local exclusive starts
    __shared__ int lcur[NBMAX];    // bump cursors, then reused as gdelta
    __shared__ int p[256];
    __shared__ int2 ord[CHUNK];
    __shared__ unsigned short obk[CHUNK];

    const int tid = threadIdx.x;
    const int base = blockIdx.x * CHUNK;
    const int n = min(CHUNK, E - base);

    for (int i = tid; i < NB; i += 256) lh[i] = 0;
    __syncthreads();

    int esv[16]; int ebk[16];
    float evv[16];
#pragma unroll
    for (int k = 0; k < 16; ++k) {
        int li = k * 256 + tid;
        if (li < n) {
            int i = base + li;
            int dst = edst[i];
            esv[k] = esrc[i];
            evv[k] = eval[i];
            int b = dst >> 7;
            ebk[k] = b | ((dst & 127) << 16);
            atomicAdd(&lh[b], 1);
        } else ebk[k] = -1;
    }
    __syncthreads();

    // scan lh[0..NB) -> lstart (exclusive), 4 elems/thread over padded 1024
    int s0 = lh[4*tid], s1 = lh[4*tid+1], s2 = lh[4*tid+2], s3 = lh[4*tid+3];
    int loc = s0 + s1 + s2 + s3;
    p[tid] = loc;
    __syncthreads();
    for (int off = 1; off < 256; off <<= 1) {
        int v = p[tid];
        int u = (tid >= off) ? p[tid - off] : 0;
        __syncthreads();
        p[tid] = v + u;
        __syncthreads();
    }
    int ex = p[tid] - loc;
    lstart[4*tid] = ex; lcur[4*tid] = ex;
    lstart[4*tid+1] = ex + s0; lcur[4*tid+1] = ex + s0;
    lstart[4*tid+2] = ex + s0 + s1; lcur[4*tid+2] = ex + s0 + s1;
    lstart[4*tid+3] = ex + s0 + s1 + s2; lcur[4*tid+3] = ex + s0 + s1 + s2;
    __syncthreads();

    // scatter into ordered LDS buffer
#pragma unroll
    for (int k = 0; k < 16; ++k) {
        if (ebk[k] >= 0) {
            int b = ebk[k] & 0xffff, nl = ebk[k] >> 16;
            int slot = atomicAdd(&lcur[b], 1);
            ord[slot] = make_int2(esv[k] | (nl << 20), __builtin_bit_cast(int, evv[k]));
            obk[slot] = (unsigned short)b;
        }
    }
    __syncthreads();

    // one global cursor bump per nonempty bucket; lcur becomes gdelta
    for (int b = tid; b < NB; b += 256) {
        int c = lh[b];
        if (c) lcur[b] = atomicAdd(&bucket_cursor[b], c) - lstart[b];
    }
    __syncthreads();

    // run-contiguous copy out
    for (int i = tid; i < n; i += 256) {
        int b = obk[i];
        edge_pack[lcur[b] + i] = ord[i];
    }
}

// One block per bucket (128 nodes). LDS fp32 accumulator 128x128.
// Lane l handles feats 2l,2l+1; ds_add addresses swizzled by quad parity so
// each instruction covers all 32 banks (2-way = free).
__global__ __launch_bounds__(256) void gather_kernel(
        const unsigned short* __restrict__ x_bf,
        const int* __restrict__ bucket_base,
        const int* __restrict__ bucket_cnt,
        const int2* __restrict__ edge_pack,
        unsigned short* __restrict__ support_bf, int N) {
    __shared__ float acc[128 * 128];   // 64 KB
    const int tid = threadIdx.x;
    const int b = blockIdx.x;
    for (int i = tid * 4; i < 128 * 128; i += 1024)
        *(float4*)(acc + i) = make_float4(0.f, 0.f, 0.f, 0.f);
    __syncthreads();

    const int start = bucket_base[b];
    const int cnt = bucket_cnt[b];
    const int node0 = b << 7;
    const int w = tid >> 6, lane = tid & 63;
    const int q1 = (lane >> 4) & 1;
    const int i0 = lane * 2 + q1;

    int j = start + (cnt * w) / 4;
    const int jend = start + (cnt * (w + 1)) / 4;

    for (; j + 2 <= jend; j += 2) {
        int2 ea = edge_pack[j];
        int2 eb = edge_pack[j + 1];
        unsigned int pa = *(const unsigned int*)(x_bf + (size_t)(ea.x & 0xFFFFF) * D + lane * 2);
        unsigned int pb = *(const unsigned int*)(x_bf + (size_t)(eb.x & 0xFFFFF) * D + lane * 2);
        float va = __builtin_bit_cast(float, ea.y);
        float vb = __builtin_bit_cast(float, eb.y);
        float a0 = bf2f(pa & 0xffffu) * va, a1 = bf2f(pa >> 16) * va;
        float b0 = bf2f(pb & 0xffffu) * vb, b1 = bf2f(pb >> 16) * vb;
        float* ra = acc + ((ea.x >> 20) & 127) * D;
        float* rb = acc + ((eb.x >> 20) & 127) * D;
        atomicAdd(&ra[i0],     q1 ? a1 : a0);
        atomicAdd(&ra[i0 ^ 1], q1 ? a0 : a1);
        atomicAdd(&rb[i0],     q1 ? b1 : b0);
        atomicAdd(&rb[i0 ^ 1], q1 ? b0 : b1);
    }
    if (j < jend) {
        int2 ea = edge_pack[j];
        unsigned int pa = *(const unsigned int*)(x_bf + (size_t)(ea.x & 0xFFFFF) * D + lane * 2);
        float va = __builtin_bit_cast(float, ea.y);
        float a0 = bf2f(pa & 0xffffu) * va, a1 = bf2f(pa >> 16) * va;
        float* ra = acc + ((ea.x >> 20) & 127) * D;
        atomicAdd(&ra[i0],     q1 ? a1 : a0);
        atomicAdd(&ra[i0 ^ 1], q1 ? a0 : a1);
    }
    __syncthreads();

    const int remain = min(128, N - node0);
    const int lim = remain * D;
    for (int i = tid * 4; i < lim; i += 1024) {
        float4 v = *(const float4*)(acc + i);
        ushort4 s; s.x = f2bf(v.x); s.y = f2bf(v.y); s.z = f2bf(v.z); s.w = f2bf(v.w);
        *(ushort4*)(support_bf + (size_t)node0 * D + i) = s;
    }
}

// Block = 256 threads (4 waves) -> 64 rows x 128 cols of out.
__global__ __launch_bounds__(256) void gemm_kernel(
        const unsigned short* __restrict__ x_bf,
        const unsigned short* __restrict__ support_bf,
        const unsigned short* __restrict__ WT,
        const float* __restrict__ bias,
        float* __restrict__ out, int N) {
    __shared__ unsigned short hA[64 * 264];
    const int tid = threadIdx.x;
    const int row0 = blockIdx.x * 64;

    for (int t = tid; t < 1024; t += 256) {
        int r = t >> 4, c = (t & 15) << 3;
        int rg = row0 + r;
        uint4 v = make_uint4(0u, 0u, 0u, 0u);
        if (rg < N) v = *(const uint4*)(x_bf + (size_t)rg * D + c);
        *(uint4*)(hA + r * 264 + c) = v;
    }
    for (int t = tid; t < 1024; t += 256) {
        int r = t >> 4, c = (t & 15) << 3;
        int rg = row0 + r;
        uint4 v = make_uint4(0u, 0u, 0u, 0u);
        if (rg < N) v = *(const uint4*)(support_bf + (size_t)rg * D + c);
        *(uint4*)(hA + r * 264 + 128 + c) = v;
    }

    const int lane = tid & 63;
    const int quad = lane >> 4;
    const int l15  = lane & 15;
    const int colbase = (tid >> 6) * 32;

    bf16x8 wfrag[2][8];
#pragma unroll
    for (int ct = 0; ct < 2; ++ct) {
        int col = colbase + ct * 16 + l15;
#pragma unroll
        for (int ks = 0; ks < 8; ++ks)
            wfrag[ct][ks] = *(const bf16x8*)(WT + (size_t)col * 256 + ks * 32 + quad * 8);
    }

    __syncthreads();

    f32x4 acc[4][2];
#pragma unroll
    for (int rt = 0; rt < 4; ++rt)
#pragma unroll
        for (int ct = 0; ct < 2; ++ct)
            acc[rt][ct] = (f32x4){0.f, 0.f, 0.f, 0.f};

#pragma unroll
    for (int ks = 0; ks < 8; ++ks) {
#pragma unroll
        for (int rt = 0; rt < 4; ++rt) {
            bf16x8 a = *(const bf16x8*)(hA + (rt * 16 + l15) * 264 + ks * 32 + quad * 8);
#pragma unroll
            for (int ct = 0; ct < 2; ++ct)
                acc[rt][ct] = __builtin_amdgcn_mfma_f32_16x16x32_bf16(
                    a, wfrag[ct][ks], acc[rt][ct], 0, 0, 0);
        }
    }

#pragma unroll
    for (int ct = 0; ct < 2; ++ct) {
        int col = colbase + ct * 16 + l15;
        float bv = bias[col];
#pragma unroll
        for (int rt = 0; rt < 4; ++rt) {
#pragma unroll
            for (int rg = 0; rg < 4; ++rg) {
                int row = row0 + rt * 16 + quad * 4 + rg;
                if (row < N)
                    out[(size_t)row * D + col] = acc[rt][ct][rg] + bv;
            }
        }
    }
}

extern "C" void kernel_launch(void* const* d_in, const int* in_sizes, int n_in,
                              void* d_out, int out_size, void* d_ws, size_t ws_size,
                              hipStream_t stream) {
    const float* x    = (const float*)d_in[0];
    const int*   esrc = (const int*)d_in[1];
    const int*   edst = (const int*)d_in[2];
    const float* eval = (const float*)d_in[3];
    const float* W    = (const float*)d_in[4];
    const float* bias = (const float*)d_in[5];
    float*       out  = (float*)d_out;

    const int N = in_sizes[0] / D;   // 100000
    const int E = in_sizes[1];       // 1600000
    const int NB = (N + 127) >> 7;   // 782 buckets of 128 nodes

    // ws layout (bytes, 256-aligned)
    char* ws = (char*)d_ws;
    unsigned short* support_bf = (unsigned short*)ws;               // 25,600,000
    unsigned short* x_bf       = (unsigned short*)(ws + 25600000);  // 25,600,000
    int2*           edge_pack  = (int2*)(ws + 51200000);            // 12,800,000
    unsigned short* WT         = (unsigned short*)(ws + 64000000);  // 65,536
    int*            bucket_cnt = (int*)(ws + 64065536);             // NB*4
    int*            bucket_base= (int*)(ws + 64069888);             // NB*4
    int*            bucket_cur = (int*)(ws + 64074240);             // NB*4

    zero_int_kernel<<<(NB + 255) / 256, 256, 0, stream>>>(bucket_cnt, NB);
    xprep_kernel<<<(N * D / 4 + 255) / 256, 256, 0, stream>>>(x, x_bf, N * D / 4);
    wprep_kernel<<<(2 * D * D) / 256, 256, 0, stream>>>(W, WT);
    bhist_kernel<<<512, 256, 0, stream>>>(edst, bucket_cnt, E, NB);
    bscan_kernel<<<1, 256, 0, stream>>>(bucket_cnt, bucket_base, bucket_cur, NB);
    bfill_kernel<<<(E + CHUNK - 1) / CHUNK, 256, 0, stream>>>(esrc, edst, eval,
                                                              bucket_cur, edge_pack, E, NB);
    gather_kernel<<<NB, 256, 0, stream>>>(x_bf, bucket_base, bucket_cnt,
                                          edge_pack, support_bf, N);
    gemm_kernel<<<(N + 63) / 64, 256, 0, stream>>>(x_bf, support_bf, WT, bias, out, N);
}

// Round 5
// 339.493 us; speedup vs baseline: 4.4931x; 4.4931x over previous
//
#include <hip/hip_runtime.h>

#define D 128
#define NBMAX 2048      // padded bucket array size (NB = 1563)
#define CHUNK 4096      // edges per bfill block
#define BN 64           // nodes per bucket
#define GCAP 3072       // edges per gather sort chunk

typedef __attribute__((ext_vector_type(8))) short bf16x8;
typedef __attribute__((ext_vector_type(4))) float f32x4;

__device__ __forceinline__ unsigned short f2bf(float f) {
    unsigned int u = __builtin_bit_cast(unsigned int, f);
    u = (u + 0x7fffu + ((u >> 16) & 1u)) >> 16;
    return (unsigned short)u;
}
__device__ __forceinline__ float bf2f(unsigned int u) {
    return __builtin_bit_cast(float, u << 16);
}

__global__ void zero_int_kernel(int* __restrict__ p, int n) {
    int i = blockIdx.x * 256 + threadIdx.x;
    if (i < n) p[i] = 0;
}

// x fp32 -> bf16 (natural layout), 4 elems/thread
__global__ void xprep_kernel(const float* __restrict__ x,
                             unsigned short* __restrict__ x_bf, int n4) {
    int i = blockIdx.x * 256 + threadIdx.x;
    if (i >= n4) return;
    float4 v = ((const float4*)x)[i];
    ushort4 s; s.x = f2bf(v.x); s.y = f2bf(v.y); s.z = f2bf(v.z); s.w = f2bf(v.w);
    ((ushort4*)x_bf)[i] = s;
}

// WT[col*256 + k] = bf16(W[k*128 + col])
__global__ void wprep_kernel(const float* __restrict__ W,
                             unsigned short* __restrict__ WT) {
    int t = blockIdx.x * 256 + threadIdx.x;   // 32768
    int col = t & 127, k = t >> 7;
    WT[col * 256 + k] = f2bf(W[k * D + col]);
}

// per-bucket histogram, LDS-merged (int LDS atomics)
__global__ __launch_bounds__(256) void bhist_kernel(const int* __restrict__ edst,
                                                    int* __restrict__ bucket_cnt,
                                                    int E, int NB) {
    __shared__ int h[NBMAX];
    for (int i = threadIdx.x; i < NB; i += 256) h[i] = 0;
    __syncthreads();
    int stride = gridDim.x * 256;
    for (int e = blockIdx.x * 256 + threadIdx.x; e < E; e += stride)
        atomicAdd(&h[edst[e] >> 6], 1);
    __syncthreads();
    for (int i = threadIdx.x; i < NB; i += 256) {
        int c = h[i];
        if (c) atomicAdd(&bucket_cnt[i], c);
    }
}

// single-block exclusive scan (8 entries/thread, up to 2048)
__global__ __launch_bounds__(256) void bscan_kernel(const int* __restrict__ cnt,
                                                    int* __restrict__ base,
                                                    int* __restrict__ cursor, int NB) {
    __shared__ int p[256];
    int t = threadIdx.x;
    int c[8]; int loc = 0;
#pragma unroll
    for (int k = 0; k < 8; ++k) {
        int i = t * 8 + k;
        c[k] = (i < NB) ? cnt[i] : 0;
        loc += c[k];
    }
    p[t] = loc;
    __syncthreads();
    for (int off = 1; off < 256; off <<= 1) {
        int v = p[t];
        int u = (t >= off) ? p[t - off] : 0;
        __syncthreads();
        p[t] = v + u;
        __syncthreads();
    }
    int ex = p[t] - loc;
#pragma unroll
    for (int k = 0; k < 8; ++k) {
        int i = t * 8 + k;
        if (i < NB) { base[i] = ex; cursor[i] = ex; }
        ex += c[k];
    }
}

// LDS counting sort of a 4096-edge chunk into contiguous per-bucket runs.
// ord.x = src | (node_local << 20), ord.y = fp32 val bits.
__global__ __launch_bounds__(256) void bfill_kernel(const int* __restrict__ esrc,
                                                    const int* __restrict__ edst,
                                                    const float* __restrict__ eval,
                                                    int* __restrict__ bucket_cursor,
                                                    int2* __restrict__ edge_pack,
                                                    int E, int NB) {
    __shared__ int lh[NBMAX];      // counts -> gdelta
    __shared__ int lcur[NBMAX];    // exclusive starts -> bump cursors -> ends
    __shared__ int p[256];
    __shared__ int2 ord[CHUNK];
    __shared__ unsigned short obk[CHUNK];

    const int tid = threadIdx.x;
    const int base = blockIdx.x * CHUNK;
    const int n = min(CHUNK, E - base);

    for (int i = tid; i < NBMAX; i += 256) lh[i] = 0;
    __syncthreads();

    int esv[16]; int ebk[16];
    float evv[16];
#pragma unroll
    for (int k = 0; k < 16; ++k) {
        int li = k * 256 + tid;
        if (li < n) {
            int i = base + li;
            int dst = edst[i];
            esv[k] = esrc[i];
            evv[k] = eval[i];
            int b = dst >> 6;
            ebk[k] = b | ((dst & 63) << 16);
            atomicAdd(&lh[b], 1);
        } else ebk[k] = -1;
    }
    __syncthreads();

    // exclusive scan of lh[0..2048) -> lcur, 8/thread
    int s[8]; int loc = 0;
#pragma unroll
    for (int k = 0; k < 8; ++k) { s[k] = lh[8 * tid + k]; loc += s[k]; }
    p[tid] = loc;
    __syncthreads();
    for (int off = 1; off < 256; off <<= 1) {
        int v = p[tid];
        int u = (tid >= off) ? p[tid - off] : 0;
        __syncthreads();
        p[tid] = v + u;
        __syncthreads();
    }
    int ex = p[tid] - loc;
#pragma unroll
    for (int k = 0; k < 8; ++k) { lcur[8 * tid + k] = ex; ex += s[k]; }
    __syncthreads();

    // scatter into ordered LDS buffer (bump lcur)
#pragma unroll
    for (int k = 0; k < 16; ++k) {
        if (ebk[k] >= 0) {
            int b = ebk[k] & 0xffff, nl = ebk[k] >> 16;
            int slot = atomicAdd(&lcur[b], 1);
            ord[slot] = make_int2(esv[k] | (nl << 20), __builtin_bit_cast(int, evv[k]));
            obk[slot] = (unsigned short)b;
        }
    }
    __syncthreads();

    // one global cursor bump per nonempty bucket; lh becomes gdelta
    // (local start of bucket b = lcur[b] - lh[b], since lcur is now the end)
    for (int b = tid; b < NB; b += 256) {
        int c = lh[b];
        if (c) lh[b] = atomicAdd(&bucket_cursor[b], c) - (lcur[b] - c);
    }
    __syncthreads();

    // run-contiguous copy out
    for (int i = tid; i < n; i += 256) {
        int b = obk[i];
        edge_pack[lh[b] + i] = ord[i];
    }
}

// One block per bucket (64 nodes). Counting-sort bucket edges by node in LDS
// (int atomics only), then each wave walks its 16 nodes' contiguous runs,
// accumulating in registers (2 floats/lane); wave-uniform flush into LDS fp32
// tile via plain RMW (disjoint node ranges per wave -> race-free).
__global__ __launch_bounds__(256) void gather_kernel(
        const unsigned short* __restrict__ x_bf,
        const int* __restrict__ bucket_base,
        const int* __restrict__ bucket_cnt,
        const int2* __restrict__ edge_pack,
        unsigned short* __restrict__ support_bf, int N) {
    __shared__ float accf[BN * D];          // 32KB
    __shared__ int2 ord[GCAP];              // 24KB
    __shared__ int cnt64[BN];
    __shared__ int start64[BN + 1];
    __shared__ int cur64[BN];

    const int tid = threadIdx.x;
    const int b = blockIdx.x;
    const int start = bucket_base[b];
    const int cnt = bucket_cnt[b];
    const int node0 = b * BN;
    const int w = tid >> 6, lane = tid & 63;

    for (int i = tid * 4; i < BN * D; i += 1024)
        *(float4*)(accf + i) = make_float4(0.f, 0.f, 0.f, 0.f);

    for (int c0 = 0; c0 < cnt; c0 += GCAP) {
        const int n = min(GCAP, cnt - c0);
        if (tid < BN) cnt64[tid] = 0;
        __syncthreads();
        for (int i = tid; i < n; i += 256) {
            int xv = edge_pack[start + c0 + i].x;
            atomicAdd(&cnt64[(xv >> 20) & 63], 1);
        }
        __syncthreads();
        if (tid < BN) {
            int c = cnt64[tid];
            int v = c;
#pragma unroll
            for (int off = 1; off < 64; off <<= 1) {
                int t = __shfl_up(v, off, 64);
                if (lane >= off) v += t;
            }
            start64[tid] = v - c;
            cur64[tid] = v - c;
            if (tid == BN - 1) start64[BN] = v;
        }
        __syncthreads();
        for (int i = tid; i < n; i += 256) {
            int2 e = edge_pack[start + c0 + i];
            int slot = atomicAdd(&cur64[(e.x >> 20) & 63], 1);
            ord[slot] = e;
        }
        __syncthreads();

        // accumulate: wave w owns nodes [w*16, w*16+16)
        int js = start64[w * 16];
        int je = start64[w * 16 + 16];
        int cur = -1;
        float ax = 0.f, ay = 0.f;
        for (int g = js; g < je; g += 8) {
            int m = je - g; if (m > 8) m = 8;
            int2 e[8];
#pragma unroll
            for (int k = 0; k < 8; ++k) {
                int idx = g + k; if (idx >= je) idx = je - 1;
                e[k] = ord[idx];
            }
            unsigned int p[8];
#pragma unroll
            for (int k = 0; k < 8; ++k)
                p[k] = *(const unsigned int*)(x_bf + (size_t)(e[k].x & 0xFFFFF) * D + lane * 2);
#pragma unroll
            for (int k = 0; k < 8; ++k) {
                if (k < m) {
                    int nd = (e[k].x >> 20) & 63;
                    if (nd != cur) {
                        if (cur >= 0) {
                            accf[cur * D + lane * 2]     += ax;
                            accf[cur * D + lane * 2 + 1] += ay;
                        }
                        cur = nd; ax = 0.f; ay = 0.f;
                    }
                    float v = __builtin_bit_cast(float, e[k].y);
                    ax += bf2f(p[k] & 0xffffu) * v;
                    ay += bf2f(p[k] >> 16) * v;
                }
            }
        }
        if (cur >= 0) {
            accf[cur * D + lane * 2]     += ax;
            accf[cur * D + lane * 2 + 1] += ay;
        }
        __syncthreads();   // before next chunk reuses cnt64/ord
    }

    int remain = N - node0; if (remain > BN) remain = BN;
    int lim = remain * D;
    for (int i = tid * 4; i < lim; i += 1024) {
        float4 v = *(const float4*)(accf + i);
        ushort4 s; s.x = f2bf(v.x); s.y = f2bf(v.y); s.z = f2bf(v.z); s.w = f2bf(v.w);
        *(ushort4*)(support_bf + (size_t)node0 * D + i) = s;
    }
}

// Block = 256 threads (4 waves) -> 64 rows x 128 cols of out.
__global__ __launch_bounds__(256) void gemm_kernel(
        const unsigned short* __restrict__ x_bf,
        const unsigned short* __restrict__ support_bf,
        const unsigned short* __restrict__ WT,
        const float* __restrict__ bias,
        float* __restrict__ out, int N) {
    __shared__ unsigned short hA[64 * 264];
    const int tid = threadIdx.x;
    const int row0 = blockIdx.x * 64;

    for (int t = tid; t < 1024; t += 256) {
        int r = t >> 4, c = (t & 15) << 3;
        int rg = row0 + r;
        uint4 v = make_uint4(0u, 0u, 0u, 0u);
        if (rg < N) v = *(const uint4*)(x_bf + (size_t)rg * D + c);
        *(uint4*)(hA + r * 264 + c) = v;
    }
    for (int t = tid; t < 1024; t += 256) {
        int r = t >> 4, c = (t & 15) << 3;
        int rg = row0 + r;
        uint4 v = make_uint4(0u, 0u, 0u, 0u);
        if (rg < N) v = *(const uint4*)(support_bf + (size_t)rg * D + c);
        *(uint4*)(hA + r * 264 + 128 + c) = v;
    }

    const int lane = tid & 63;
    const int quad = lane >> 4;
    const int l15  = lane & 15;
    const int colbase = (tid >> 6) * 32;

    bf16x8 wfrag[2][8];
#pragma unroll
    for (int ct = 0; ct < 2; ++ct) {
        int col = colbase + ct * 16 + l15;
#pragma unroll
        for (int ks = 0; ks < 8; ++ks)
            wfrag[ct][ks] = *(const bf16x8*)(WT + (size_t)col * 256 + ks * 32 + quad * 8);
    }

    __syncthreads();

    f32x4 acc[4][2];
#pragma unroll
    for (int rt = 0; rt < 4; ++rt)
#pragma unroll
        for (int ct = 0; ct < 2; ++ct)
            acc[rt][ct] = (f32x4){0.f, 0.f, 0.f, 0.f};

#pragma unroll
    for (int ks = 0; ks < 8; ++ks) {
#pragma unroll
        for (int rt = 0; rt < 4; ++rt) {
            bf16x8 a = *(const bf16x8*)(hA + (rt * 16 + l15) * 264 + ks * 32 + quad * 8);
#pragma unroll
            for (int ct = 0; ct < 2; ++ct)
                acc[rt][ct] = __builtin_amdgcn_mfma_f32_16x16x32_bf16(
                    a, wfrag[ct][ks], acc[rt][ct], 0, 0, 0);
        }
    }

#pragma unroll
    for (int ct = 0; ct < 2; ++ct) {
        int col = colbase + ct * 16 + l15;
        float bv = bias[col];
#pragma unroll
        for (int rt = 0; rt < 4; ++rt) {
#pragma unroll
            for (int rg = 0; rg < 4; ++rg) {
                int row = row0 + rt * 16 + quad * 4 + rg;
                if (row < N)
                    out[(size_t)row * D + col] = acc[rt][ct][rg] + bv;
            }
        }
    }
}

extern "C" void kernel_launch(void* const* d_in, const int* in_sizes, int n_in,
                              void* d_out, int out_size, void* d_ws, size_t ws_size,
                              hipStream_t stream) {
    const float* x    = (const float*)d_in[0];
    const int*   esrc = (const int*)d_in[1];
    const int*   edst = (const int*)d_in[2];
    const float* eval = (const float*)d_in[3];
    const float* W    = (const float*)d_in[4];
    const float* bias = (const float*)d_in[5];
    float*       out  = (float*)d_out;

    const int N = in_sizes[0] / D;   // 100000
    const int E = in_sizes[1];       // 1600000
    const int NB = (N + BN - 1) / BN; // 1563 buckets of 64 nodes

    // ws layout (bytes)
    char* ws = (char*)d_ws;
    unsigned short* support_bf = (unsigned short*)ws;               // 25,600,000
    unsigned short* x_bf       = (unsigned short*)(ws + 25600000);  // 25,600,000
    int2*           edge_pack  = (int2*)(ws + 51200000);            // 12,800,000
    unsigned short* WT         = (unsigned short*)(ws + 64000000);  // 65,536
    int*            bucket_cnt = (int*)(ws + 64065536);             // NB*4
    int*            bucket_base= (int*)(ws + 64073728);             // NB*4
    int*            bucket_cur = (int*)(ws + 64081920);             // NB*4

    zero_int_kernel<<<(NB + 255) / 256, 256, 0, stream>>>(bucket_cnt, NB);
    xprep_kernel<<<(N * D / 4 + 255) / 256, 256, 0, stream>>>(x, x_bf, N * D / 4);
    wprep_kernel<<<(2 * D * D) / 256, 256, 0, stream>>>(W, WT);
    bhist_kernel<<<512, 256, 0, stream>>>(edst, bucket_cnt, E, NB);
    bscan_kernel<<<1, 256, 0, stream>>>(bucket_cnt, bucket_base, bucket_cur, NB);
    bfill_kernel<<<(E + CHUNK - 1) / CHUNK, 256, 0, stream>>>(esrc, edst, eval,
                                                              bucket_cur, edge_pack, E, NB);
    gather_kernel<<<NB, 256, 0, stream>>>(x_bf, bucket_base, bucket_cnt,
                                          edge_pack, support_bf, N);
    gemm_kernel<<<(N + 63) / 64, 256, 0, stream>>>(x_bf, support_bf, WT, bias, out, N);
}

// Round 6
// 315.357 us; speedup vs baseline: 4.8370x; 1.0765x over previous
//
#include <hip/hip_runtime.h>

#define D 128
#define NBMAX 2048      // padded bucket array size (NB = 1563)
#define CHUNK 4096      // edges per bfill block
#define BN 64           // nodes per bucket
#define GCAP 4096       // edges per gather sort chunk (perm is ushort!)

typedef __attribute__((ext_vector_type(8))) short bf16x8;
typedef __attribute__((ext_vector_type(4))) float f32x4;

__device__ __forceinline__ unsigned short f2bf(float f) {
    unsigned int u = __builtin_bit_cast(unsigned int, f);
    u = (u + 0x7fffu + ((u >> 16) & 1u)) >> 16;
    return (unsigned short)u;
}
__device__ __forceinline__ float bf2f(unsigned int u) {
    return __builtin_bit_cast(float, u << 16);
}

__global__ void zero_int_kernel(int* __restrict__ p, int n) {
    int i = blockIdx.x * 256 + threadIdx.x;
    if (i < n) p[i] = 0;
}

// x fp32 -> bf16 (natural layout), 4 elems/thread
__global__ void xprep_kernel(const float* __restrict__ x,
                             unsigned short* __restrict__ x_bf, int n4) {
    int i = blockIdx.x * 256 + threadIdx.x;
    if (i >= n4) return;
    float4 v = ((const float4*)x)[i];
    ushort4 s; s.x = f2bf(v.x); s.y = f2bf(v.y); s.z = f2bf(v.z); s.w = f2bf(v.w);
    ((ushort4*)x_bf)[i] = s;
}

// WT[col*256 + k] = bf16(W[k*128 + col])
__global__ void wprep_kernel(const float* __restrict__ W,
                             unsigned short* __restrict__ WT) {
    int t = blockIdx.x * 256 + threadIdx.x;   // 32768
    int col = t & 127, k = t >> 7;
    WT[col * 256 + k] = f2bf(W[k * D + col]);
}

// per-bucket histogram, LDS-merged (int LDS atomics)
__global__ __launch_bounds__(256) void bhist_kernel(const int* __restrict__ edst,
                                                    int* __restrict__ bucket_cnt,
                                                    int E, int NB) {
    __shared__ int h[NBMAX];
    for (int i = threadIdx.x; i < NB; i += 256) h[i] = 0;
    __syncthreads();
    int stride = gridDim.x * 256;
    for (int e = blockIdx.x * 256 + threadIdx.x; e < E; e += stride)
        atomicAdd(&h[edst[e] >> 6], 1);
    __syncthreads();
    for (int i = threadIdx.x; i < NB; i += 256) {
        int c = h[i];
        if (c) atomicAdd(&bucket_cnt[i], c);
    }
}

// single-block exclusive scan (8 entries/thread, up to 2048)
__global__ __launch_bounds__(256) void bscan_kernel(const int* __restrict__ cnt,
                                                    int* __restrict__ base,
                                                    int* __restrict__ cursor, int NB) {
    __shared__ int p[256];
    int t = threadIdx.x;
    int c[8]; int loc = 0;
#pragma unroll
    for (int k = 0; k < 8; ++k) {
        int i = t * 8 + k;
        c[k] = (i < NB) ? cnt[i] : 0;
        loc += c[k];
    }
    p[t] = loc;
    __syncthreads();
    for (int off = 1; off < 256; off <<= 1) {
        int v = p[t];
        int u = (t >= off) ? p[t - off] : 0;
        __syncthreads();
        p[t] = v + u;
        __syncthreads();
    }
    int ex = p[t] - loc;
#pragma unroll
    for (int k = 0; k < 8; ++k) {
        int i = t * 8 + k;
        if (i < NB) { base[i] = ex; cursor[i] = ex; }
        ex += c[k];
    }
}

// LDS counting sort of a 4096-edge chunk into contiguous per-bucket runs.
// ord.x = src | (node_local << 20), ord.y = fp32 val bits.
__global__ __launch_bounds__(256) void bfill_kernel(const int* __restrict__ esrc,
                                                    const int* __restrict__ edst,
                                                    const float* __restrict__ eval,
                                                    int* __restrict__ bucket_cursor,
                                                    int2* __restrict__ edge_pack,
                                                    int E, int NB) {
    __shared__ int lh[NBMAX];      // counts -> gdelta
    __shared__ int lcur[NBMAX];    // exclusive starts -> bump cursors -> ends
    __shared__ int p[256];
    __shared__ int2 ord[CHUNK];
    __shared__ unsigned short obk[CHUNK];

    const int tid = threadIdx.x;
    const int base = blockIdx.x * CHUNK;
    const int n = min(CHUNK, E - base);

    for (int i = tid; i < NBMAX; i += 256) lh[i] = 0;
    __syncthreads();

    int esv[16]; int ebk[16];
    float evv[16];
#pragma unroll
    for (int k = 0; k < 16; ++k) {
        int li = k * 256 + tid;
        if (li < n) {
            int i = base + li;
            int dst = edst[i];
            esv[k] = esrc[i];
            evv[k] = eval[i];
            int b = dst >> 6;
            ebk[k] = b | ((dst & 63) << 16);
            atomicAdd(&lh[b], 1);
        } else ebk[k] = -1;
    }
    __syncthreads();

    // exclusive scan of lh[0..2048) -> lcur, 8/thread
    int s[8]; int loc = 0;
#pragma unroll
    for (int k = 0; k < 8; ++k) { s[k] = lh[8 * tid + k]; loc += s[k]; }
    p[tid] = loc;
    __syncthreads();
    for (int off = 1; off < 256; off <<= 1) {
        int v = p[tid];
        int u = (tid >= off) ? p[tid - off] : 0;
        __syncthreads();
        p[tid] = v + u;
        __syncthreads();
    }
    int ex = p[tid] - loc;
#pragma unroll
    for (int k = 0; k < 8; ++k) { lcur[8 * tid + k] = ex; ex += s[k]; }
    __syncthreads();

    // scatter into ordered LDS buffer (bump lcur)
#pragma unroll
    for (int k = 0; k < 16; ++k) {
        if (ebk[k] >= 0) {
            int b = ebk[k] & 0xffff, nl = ebk[k] >> 16;
            int slot = atomicAdd(&lcur[b], 1);
            ord[slot] = make_int2(esv[k] | (nl << 20), __builtin_bit_cast(int, evv[k]));
            obk[slot] = (unsigned short)b;
        }
    }
    __syncthreads();

    // one global cursor bump per nonempty bucket; lh becomes gdelta
    for (int b = tid; b < NB; b += 256) {
        int c = lh[b];
        if (c) lh[b] = atomicAdd(&bucket_cursor[b], c) - (lcur[b] - c);
    }
    __syncthreads();

    // run-contiguous copy out
    for (int i = tid; i < n; i += 256) {
        int b = obk[i];
        edge_pack[lh[b] + i] = ord[i];
    }
}

// One block per bucket (64 nodes). Phase 1: counting-sort the bucket's edges
// by node (ushort perm in LDS, int atomics only); each wave walks its 16
// nodes' contiguous runs accumulating in fp32 registers, flushing node
// subtotals into a bf16 LDS tile (race-free: waves own disjoint node rows;
// wave-uniform node per flush -> 2-way banks = free). Phase 2: fused GEMM --
// support A-fragments straight from the LDS tile, x A-fragments and W
// B-fragments straight from L2-hot globals (no staging), MFMA, write out.
__global__ __launch_bounds__(256, 4) void gather_fused_kernel(
        const unsigned short* __restrict__ x_bf,
        const int* __restrict__ bucket_base,
        const int* __restrict__ bucket_cnt,
        const int2* __restrict__ edge_pack,
        const unsigned short* __restrict__ WT,
        const float* __restrict__ bias,
        float* __restrict__ out, int N) {
    __shared__ unsigned short accb[BN * 136];   // bf16 accum tile, 17408 B
    __shared__ unsigned short perm[GCAP];       // 8192 B
    __shared__ int cnt64[BN];
    __shared__ int start64[BN + 1];
    __shared__ int cur64[BN];

    const int tid = threadIdx.x;
    const int b = blockIdx.x;
    const int start = bucket_base[b];
    const int cnt = bucket_cnt[b];
    const int node0 = b * BN;
    const int w = tid >> 6, lane = tid & 63;
    unsigned int* accw = (unsigned int*)accb;   // word l of row r = feats 2l,2l+1

    for (int i = tid * 8; i < BN * 136; i += 2048)
        *(uint4*)(accb + i) = make_uint4(0u, 0u, 0u, 0u);

    for (int c0 = 0; c0 < cnt; c0 += GCAP) {
        const int n = min(GCAP, cnt - c0);
        if (tid < BN) cnt64[tid] = 0;
        __syncthreads();
        for (int i = tid; i < n; i += 256)
            atomicAdd(&cnt64[(edge_pack[start + c0 + i].x >> 20) & 63], 1);
        __syncthreads();
        if (tid < BN) {
            int c = cnt64[tid];
            int v = c;
#pragma unroll
            for (int off = 1; off < 64; off <<= 1) {
                int t = __shfl_up(v, off, 64);
                if (lane >= off) v += t;
            }
            start64[tid] = v - c;
            cur64[tid] = v - c;
            if (tid == BN - 1) start64[BN] = v;
        }
        __syncthreads();
        for (int i = tid; i < n; i += 256) {
            int nd = (edge_pack[start + c0 + i].x >> 20) & 63;
            perm[atomicAdd(&cur64[nd], 1)] = (unsigned short)i;
        }
        __syncthreads();

        // accumulate: wave w owns nodes [w*16, w*16+16)
        const int js = start64[w * 16];
        const int je = start64[w * 16 + 16];
        int cur = -1;
        float ax = 0.f, ay = 0.f;
        for (int g = js; g < je; g += 8) {
            int m = je - g; if (m > 8) m = 8;
            int2 e[8];
#pragma unroll
            for (int k = 0; k < 8; ++k) {
                int idx = g + k; if (idx >= je) idx = je - 1;
                e[k] = edge_pack[start + c0 + perm[idx]];   // L1-hot window
            }
            unsigned int p[8];
#pragma unroll
            for (int k = 0; k < 8; ++k)
                p[k] = *(const unsigned int*)(x_bf + (size_t)(e[k].x & 0xFFFFF) * D + lane * 2);
#pragma unroll
            for (int k = 0; k < 8; ++k) {
                if (k < m) {
                    int nd = (e[k].x >> 20) & 63;
                    if (nd != cur) {
                        if (cur >= 0) {
                            unsigned int o = accw[cur * 68 + lane];
                            float o0 = bf2f(o & 0xffffu) + ax;
                            float o1 = bf2f(o >> 16) + ay;
                            accw[cur * 68 + lane] =
                                (unsigned int)f2bf(o0) | ((unsigned int)f2bf(o1) << 16);
                        }
                        cur = nd; ax = 0.f; ay = 0.f;
                    }
                    float v = __builtin_bit_cast(float, e[k].y);
                    ax += bf2f(p[k] & 0xffffu) * v;
                    ay += bf2f(p[k] >> 16) * v;
                }
            }
        }
        if (cur >= 0) {
            unsigned int o = accw[cur * 68 + lane];
            float o0 = bf2f(o & 0xffffu) + ax;
            float o1 = bf2f(o >> 16) + ay;
            accw[cur * 68 + lane] = (unsigned int)f2bf(o0) | ((unsigned int)f2bf(o1) << 16);
        }
        __syncthreads();   // before next chunk reuses cnt64/perm
    }

    // ---- fused GEMM phase: out[node0..node0+64) = [x | accb] @ W + b ----
    const int quad = lane >> 4;
    const int l15  = lane & 15;
    const int colbase = w * 32;

    f32x4 acc[4][2];
#pragma unroll
    for (int rt = 0; rt < 4; ++rt) {
        acc[rt][0] = (f32x4){0.f, 0.f, 0.f, 0.f};
        acc[rt][1] = (f32x4){0.f, 0.f, 0.f, 0.f};
    }

#pragma unroll
    for (int ks = 0; ks < 8; ++ks) {
        bf16x8 wf0 = *(const bf16x8*)(WT + (size_t)(colbase + l15) * 256 + ks * 32 + quad * 8);
        bf16x8 wf1 = *(const bf16x8*)(WT + (size_t)(colbase + 16 + l15) * 256 + ks * 32 + quad * 8);
#pragma unroll
        for (int rt = 0; rt < 4; ++rt) {
            int row = rt * 16 + l15;
            bf16x8 a;
            if (ks < 4) {
                int rg = node0 + row; if (rg >= N) rg = N - 1;   // garbage rows unused
                a = *(const bf16x8*)(x_bf + (size_t)rg * D + ks * 32 + quad * 8);
            } else {
                a = *(const bf16x8*)(accb + row * 136 + (ks - 4) * 32 + quad * 8);
            }
            acc[rt][0] = __builtin_amdgcn_mfma_f32_16x16x32_bf16(a, wf0, acc[rt][0], 0, 0, 0);
            acc[rt][1] = __builtin_amdgcn_mfma_f32_16x16x32_bf16(a, wf1, acc[rt][1], 0, 0, 0);
        }
    }

#pragma unroll
    for (int ct = 0; ct < 2; ++ct) {
        int col = colbase + ct * 16 + l15;
        float bv = bias[col];
#pragma unroll
        for (int rt = 0; rt < 4; ++rt) {
#pragma unroll
            for (int rg = 0; rg < 4; ++rg) {
                int row = node0 + rt * 16 + quad * 4 + rg;
                if (row < N)
                    out[(size_t)row * D + col] = acc[rt][ct][rg] + bv;
            }
        }
    }
}

extern "C" void kernel_launch(void* const* d_in, const int* in_sizes, int n_in,
                              void* d_out, int out_size, void* d_ws, size_t ws_size,
                              hipStream_t stream) {
    const float* x    = (const float*)d_in[0];
    const int*   esrc = (const int*)d_in[1];
    const int*   edst = (const int*)d_in[2];
    const float* eval = (const float*)d_in[3];
    const float* W    = (const float*)d_in[4];
    const float* bias = (const float*)d_in[5];
    float*       out  = (float*)d_out;

    const int N = in_sizes[0] / D;    // 100000
    const int E = in_sizes[1];        // 1600000
    const int NB = (N + BN - 1) / BN; // 1563 buckets of 64 nodes

    // ws layout (bytes)
    char* ws = (char*)d_ws;
    unsigned short* x_bf       = (unsigned short*)ws;               // 25,600,000
    int2*           edge_pack  = (int2*)(ws + 25600000);            // 12,800,000
    unsigned short* WT         = (unsigned short*)(ws + 38400000);  // 65,536
    int*            bucket_cnt = (int*)(ws + 38465536);             // NB*4
    int*            bucket_base= (int*)(ws + 38473728);             // NB*4
    int*            bucket_cur = (int*)(ws + 38481920);             // NB*4

    zero_int_kernel<<<(NB + 255) / 256, 256, 0, stream>>>(bucket_cnt, NB);
    xprep_kernel<<<(N * D / 4 + 255) / 256, 256, 0, stream>>>(x, x_bf, N * D / 4);
    wprep_kernel<<<(2 * D * D) / 256, 256, 0, stream>>>(W, WT);
    bhist_kernel<<<512, 256, 0, stream>>>(edst, bucket_cnt, E, NB);
    bscan_kernel<<<1, 256, 0, stream>>>(bucket_cnt, bucket_base, bucket_cur, NB);
    bfill_kernel<<<(E + CHUNK - 1) / CHUNK, 256, 0, stream>>>(esrc, edst, eval,
                                                              bucket_cur, edge_pack, E, NB);
    gather_fused_kernel<<<NB, 256, 0, stream>>>(x_bf, bucket_base, bucket_cnt,
                                                edge_pack, WT, bias, out, N);
}

// Round 7
// 278.095 us; speedup vs baseline: 5.4851x; 1.1340x over previous
//
#include <hip/hip_runtime.h>

#define D 128
#define NBMAX 2048      // padded bucket array size (NB = 1563)
#define CHUNK 2048      // edges per bfill block
#define BN 64           // nodes per bucket
#define GCAP 2048       // edges per gather sort chunk (LDS int2)

typedef __attribute__((ext_vector_type(8))) short bf16x8;
typedef __attribute__((ext_vector_type(4))) float f32x4;

__device__ __forceinline__ unsigned short f2bf(float f) {
    unsigned int u = __builtin_bit_cast(unsigned int, f);
    u = (u + 0x7fffu + ((u >> 16) & 1u)) >> 16;
    return (unsigned short)u;
}
__device__ __forceinline__ float bf2f(unsigned int u) {
    return __builtin_bit_cast(float, u << 16);
}

__global__ void zero_int_kernel(int* __restrict__ p, int n) {
    int i = blockIdx.x * 256 + threadIdx.x;
    if (i < n) p[i] = 0;
}

// x fp32 -> bf16 (natural layout), 4 elems/thread
__global__ void xprep_kernel(const float* __restrict__ x,
                             unsigned short* __restrict__ x_bf, int n4) {
    int i = blockIdx.x * 256 + threadIdx.x;
    if (i >= n4) return;
    float4 v = ((const float4*)x)[i];
    ushort4 s; s.x = f2bf(v.x); s.y = f2bf(v.y); s.z = f2bf(v.z); s.w = f2bf(v.w);
    ((ushort4*)x_bf)[i] = s;
}

// WT[col*256 + k] = bf16(W[k*128 + col])
__global__ void wprep_kernel(const float* __restrict__ W,
                             unsigned short* __restrict__ WT) {
    int t = blockIdx.x * 256 + threadIdx.x;   // 32768
    int col = t & 127, k = t >> 7;
    WT[col * 256 + k] = f2bf(W[k * D + col]);
}

// per-bucket histogram, LDS-merged (int LDS atomics)
__global__ __launch_bounds__(256) void bhist_kernel(const int* __restrict__ edst,
                                                    int* __restrict__ bucket_cnt,
                                                    int E, int NB) {
    __shared__ int h[NBMAX];
    for (int i = threadIdx.x; i < NB; i += 256) h[i] = 0;
    __syncthreads();
    int stride = gridDim.x * 256;
    for (int e = blockIdx.x * 256 + threadIdx.x; e < E; e += stride)
        atomicAdd(&h[edst[e] >> 6], 1);
    __syncthreads();
    for (int i = threadIdx.x; i < NB; i += 256) {
        int c = h[i];
        if (c) atomicAdd(&bucket_cnt[i], c);
    }
}

// single-block exclusive scan (8 entries/thread, up to 2048)
__global__ __launch_bounds__(256) void bscan_kernel(const int* __restrict__ cnt,
                                                    int* __restrict__ base,
                                                    int* __restrict__ cursor, int NB) {
    __shared__ int p[256];
    int t = threadIdx.x;
    int c[8]; int loc = 0;
#pragma unroll
    for (int k = 0; k < 8; ++k) {
        int i = t * 8 + k;
        c[k] = (i < NB) ? cnt[i] : 0;
        loc += c[k];
    }
    p[t] = loc;
    __syncthreads();
    for (int off = 1; off < 256; off <<= 1) {
        int v = p[t];
        int u = (t >= off) ? p[t - off] : 0;
        __syncthreads();
        p[t] = v + u;
        __syncthreads();
    }
    int ex = p[t] - loc;
#pragma unroll
    for (int k = 0; k < 8; ++k) {
        int i = t * 8 + k;
        if (i < NB) { base[i] = ex; cursor[i] = ex; }
        ex += c[k];
    }
}

// LDS counting sort of a 2048-edge chunk into contiguous per-bucket runs.
// ord.x = src | (node_local << 20), ord.y = fp32 val bits.
__global__ __launch_bounds__(256) void bfill_kernel(const int* __restrict__ esrc,
                                                    const int* __restrict__ edst,
                                                    const float* __restrict__ eval,
                                                    int* __restrict__ bucket_cursor,
                                                    int2* __restrict__ edge_pack,
                                                    int E, int NB) {
    __shared__ int lh[NBMAX];      // counts -> gdelta
    __shared__ int lcur[NBMAX];    // exclusive starts -> bump cursors -> ends
    __shared__ int p[256];
    __shared__ int2 ord[CHUNK];
    __shared__ unsigned short obk[CHUNK];

    const int tid = threadIdx.x;
    const int base = blockIdx.x * CHUNK;
    const int n = min(CHUNK, E - base);

    for (int i = tid; i < NBMAX; i += 256) lh[i] = 0;
    __syncthreads();

    int esv[8]; int ebk[8];
    float evv[8];
#pragma unroll
    for (int k = 0; k < 8; ++k) {
        int li = k * 256 + tid;
        if (li < n) {
            int i = base + li;
            int dst = edst[i];
            esv[k] = esrc[i];
            evv[k] = eval[i];
            int b = dst >> 6;
            ebk[k] = b | ((dst & 63) << 16);
            atomicAdd(&lh[b], 1);
        } else ebk[k] = -1;
    }
    __syncthreads();

    // exclusive scan of lh[0..2048) -> lcur, 8/thread
    int s[8]; int loc = 0;
#pragma unroll
    for (int k = 0; k < 8; ++k) { s[k] = lh[8 * tid + k]; loc += s[k]; }
    p[tid] = loc;
    __syncthreads();
    for (int off = 1; off < 256; off <<= 1) {
        int v = p[tid];
        int u = (tid >= off) ? p[tid - off] : 0;
        __syncthreads();
        p[tid] = v + u;
        __syncthreads();
    }
    int ex = p[tid] - loc;
#pragma unroll
    for (int k = 0; k < 8; ++k) { lcur[8 * tid + k] = ex; ex += s[k]; }
    __syncthreads();

    // scatter into ordered LDS buffer (bump lcur)
#pragma unroll
    for (int k = 0; k < 8; ++k) {
        if (ebk[k] >= 0) {
            int b = ebk[k] & 0xffff, nl = ebk[k] >> 16;
            int slot = atomicAdd(&lcur[b], 1);
            ord[slot] = make_int2(esv[k] | (nl << 20), __builtin_bit_cast(int, evv[k]));
            obk[slot] = (unsigned short)b;
        }
    }
    __syncthreads();

    // one global cursor bump per nonempty bucket; lh becomes gdelta
    for (int b = tid; b < NB; b += 256) {
        int c = lh[b];
        if (c) lh[b] = atomicAdd(&bucket_cursor[b], c) - (lcur[b] - c);
    }
    __syncthreads();

    // run-contiguous copy out
    for (int i = tid; i < n; i += 256) {
        int b = obk[i];
        edge_pack[lh[b] + i] = ord[i];
    }
}

// One block per bucket (64 nodes). Phase 1: counting-sort the bucket's edges
// by node into LDS int2 ord[] (int atomics only); each wave walks its 16
// nodes' contiguous runs accumulating in fp32 registers (16-deep x-load
// batches for MLP), flushing node subtotals into a bf16 LDS tile (race-free:
// waves own disjoint node rows; wave-uniform flush -> 2-way banks = free).
// Phase 2: fused GEMM -- support A-fragments from the LDS tile, x A-fragments
// and W B-fragments straight from L2-hot globals, MFMA, write out.
__global__ __launch_bounds__(256, 4) void gather_fused_kernel(
        const unsigned short* __restrict__ x_bf,
        const int* __restrict__ bucket_base,
        const int* __restrict__ bucket_cnt,
        const int2* __restrict__ edge_pack,
        const unsigned short* __restrict__ WT,
        const float* __restrict__ bias,
        float* __restrict__ out, int N) {
    __shared__ unsigned short accb[BN * 136];   // bf16 accum tile, 17408 B
    __shared__ int2 ord[GCAP];                  // 16384 B
    __shared__ int cnt64[BN];
    __shared__ int start64[BN + 1];
    __shared__ int cur64[BN];

    const int tid = threadIdx.x;
    const int b = blockIdx.x;
    const int start = bucket_base[b];
    const int cnt = bucket_cnt[b];
    const int node0 = b * BN;
    const int w = tid >> 6, lane = tid & 63;
    unsigned int* accw = (unsigned int*)accb;   // word l of row r = feats 2l,2l+1

    for (int i = tid * 8; i < BN * 136; i += 2048)
        *(uint4*)(accb + i) = make_uint4(0u, 0u, 0u, 0u);

    for (int c0 = 0; c0 < cnt; c0 += GCAP) {
        const int n = min(GCAP, cnt - c0);
        if (tid < BN) cnt64[tid] = 0;
        __syncthreads();
        for (int i = tid; i < n; i += 256)
            atomicAdd(&cnt64[(edge_pack[start + c0 + i].x >> 20) & 63], 1);
        __syncthreads();
        if (tid < BN) {
            int c = cnt64[tid];
            int v = c;
#pragma unroll
            for (int off = 1; off < 64; off <<= 1) {
                int t = __shfl_up(v, off, 64);
                if (lane >= off) v += t;
            }
            start64[tid] = v - c;
            cur64[tid] = v - c;
            if (tid == BN - 1) start64[BN] = v;
        }
        __syncthreads();
        for (int i = tid; i < n; i += 256) {
            int2 e = edge_pack[start + c0 + i];
            ord[atomicAdd(&cur64[(e.x >> 20) & 63], 1)] = e;
        }
        __syncthreads();

        // accumulate: wave w owns nodes [w*16, w*16+16)
        const int js = start64[w * 16];
        const int je = start64[w * 16 + 16];
        int cur = -1;
        float ax = 0.f, ay = 0.f;
        for (int g = js; g < je; g += 16) {
            int m = je - g; if (m > 16) m = 16;
            int2 e[16];
#pragma unroll
            for (int k = 0; k < 16; ++k) {
                int idx = g + k; if (idx >= je) idx = je - 1;
                e[k] = ord[idx];
            }
            unsigned int p[16];
#pragma unroll
            for (int k = 0; k < 16; ++k)
                p[k] = *(const unsigned int*)(x_bf + (size_t)(e[k].x & 0xFFFFF) * D + lane * 2);
#pragma unroll
            for (int k = 0; k < 16; ++k) {
                if (k < m) {
                    int nd = (e[k].x >> 20) & 63;
                    if (nd != cur) {
                        if (cur >= 0) {
                            unsigned int o = accw[cur * 68 + lane];
                            float o0 = bf2f(o & 0xffffu) + ax;
                            float o1 = bf2f(o >> 16) + ay;
                            accw[cur * 68 + lane] =
                                (unsigned int)f2bf(o0) | ((unsigned int)f2bf(o1) << 16);
                        }
                        cur = nd; ax = 0.f; ay = 0.f;
                    }
                    float v = __builtin_bit_cast(float, e[k].y);
                    ax += bf2f(p[k] & 0xffffu) * v;
                    ay += bf2f(p[k] >> 16) * v;
                }
            }
        }
        if (cur >= 0) {
            unsigned int o = accw[cur * 68 + lane];
            float o0 = bf2f(o & 0xffffu) + ax;
            float o1 = bf2f(o >> 16) + ay;
            accw[cur * 68 + lane] = (unsigned int)f2bf(o0) | ((unsigned int)f2bf(o1) << 16);
        }
        __syncthreads();   // before next chunk reuses cnt64/ord
    }

    // ---- fused GEMM phase: out[node0..node0+64) = [x | accb] @ W + b ----
    const int quad = lane >> 4;
    const int l15  = lane & 15;
    const int colbase = w * 32;

    f32x4 acc[4][2];
#pragma unroll
    for (int rt = 0; rt < 4; ++rt) {
        acc[rt][0] = (f32x4){0.f, 0.f, 0.f, 0.f};
        acc[rt][1] = (f32x4){0.f, 0.f, 0.f, 0.f};
    }

#pragma unroll
    for (int ks = 0; ks < 8; ++ks) {
        bf16x8 wf0 = *(const bf16x8*)(WT + (size_t)(colbase + l15) * 256 + ks * 32 + quad * 8);
        bf16x8 wf1 = *(const bf16x8*)(WT + (size_t)(colbase + 16 + l15) * 256 + ks * 32 + quad * 8);
#pragma unroll
        for (int rt = 0; rt < 4; ++rt) {
            int row = rt * 16 + l15;
            bf16x8 a;
            if (ks < 4) {
                int rg = node0 + row; if (rg >= N) rg = N - 1;   // garbage rows unused
                a = *(const bf16x8*)(x_bf + (size_t)rg * D + ks * 32 + quad * 8);
            } else {
                a = *(const bf16x8*)(accb + row * 136 + (ks - 4) * 32 + quad * 8);
            }
            acc[rt][0] = __builtin_amdgcn_mfma_f32_16x16x32_bf16(a, wf0, acc[rt][0], 0, 0, 0);
            acc[rt][1] = __builtin_amdgcn_mfma_f32_16x16x32_bf16(a, wf1, acc[rt][1], 0, 0, 0);
        }
    }

#pragma unroll
    for (int ct = 0; ct < 2; ++ct) {
        int col = colbase + ct * 16 + l15;
        float bv = bias[col];
#pragma unroll
        for (int rt = 0; rt < 4; ++rt) {
#pragma unroll
            for (int rg = 0; rg < 4; ++rg) {
                int row = node0 + rt * 16 + quad * 4 + rg;
                if (row < N)
                    out[(size_t)row * D + col] = acc[rt][ct][rg] + bv;
            }
        }
    }
}

extern "C" void kernel_launch(void* const* d_in, const int* in_sizes, int n_in,
                              void* d_out, int out_size, void* d_ws, size_t ws_size,
                              hipStream_t stream) {
    const float* x    = (const float*)d_in[0];
    const int*   esrc = (const int*)d_in[1];
    const int*   edst = (const int*)d_in[2];
    const float* eval = (const float*)d_in[3];
    const float* W    = (const float*)d_in[4];
    const float* bias = (const float*)d_in[5];
    float*       out  = (float*)d_out;

    const int N = in_sizes[0] / D;    // 100000
    const int E = in_sizes[1];        // 1600000
    const int NB = (N + BN - 1) / BN; // 1563 buckets of 64 nodes

    // ws layout (bytes)
    char* ws = (char*)d_ws;
    unsigned short* x_bf       = (unsigned short*)ws;               // 25,600,000
    int2*           edge_pack  = (int2*)(ws + 25600000);            // 12,800,000
    unsigned short* WT         = (unsigned short*)(ws + 38400000);  // 65,536
    int*            bucket_cnt = (int*)(ws + 38465536);             // NB*4
    int*            bucket_base= (int*)(ws + 38473728);             // NB*4
    int*            bucket_cur = (int*)(ws + 38481920);             // NB*4

    zero_int_kernel<<<(NB + 255) / 256, 256, 0, stream>>>(bucket_cnt, NB);
    xprep_kernel<<<(N * D / 4 + 255) / 256, 256, 0, stream>>>(x, x_bf, N * D / 4);
    wprep_kernel<<<(2 * D * D) / 256, 256, 0, stream>>>(W, WT);
    bhist_kernel<<<512, 256, 0, stream>>>(edst, bucket_cnt, E, NB);
    bscan_kernel<<<1, 256, 0, stream>>>(bucket_cnt, bucket_base, bucket_cur, NB);
    bfill_kernel<<<(E + CHUNK - 1) / CHUNK, 256, 0, stream>>>(esrc, edst, eval,
                                                              bucket_cur, edge_pack, E, NB);
    gather_fused_kernel<<<NB, 256, 0, stream>>>(x_bf, bucket_base, bucket_cnt,
                                                edge_pack, WT, bias, out, N);
}